// Round 13
// baseline (246.786 us; speedup 1.0000x reference)
//
#include <hip/hip_runtime.h>
#include <hip/hip_bf16.h>
#include <hip/hip_fp16.h>
#include <math.h>

// Problem constants (MemN2N): B=256, M=50, L=50, V=50257, D=128, HOPS=3
#define PB   256
#define PM   50
#define PL   50
#define PV   50257
#define PD   128
#define PBM  (PB * PM)              // 12800
#define TS   ((size_t)PV * PD)      // one embedding table, elements
#define PEC  0.000625f              // 4/(D*L) = 4/6400
#define NT   786                    // ceil(PV/64) column tiles
#define PVP  (NT * 64)              // 50304 padded vocab
#define NCH  8                      // vocab chunks (~3.2 MB window/table)
#define CHW  6283                   // ceil(PV/NCH); 8*6283 = 50264 >= PV
#define UPB  50                     // bm units per gather block
#define NGB  1024                   // phase-locked gather blocks
#define NCV  393                    // convW tail blocks (128 cols each)

typedef _Float16 f16x8 __attribute__((ext_vector_type(8)));
typedef float    f32x4 __attribute__((ext_vector_type(4)));

// -------------------------------------------------------------------------
// Kernel 1: fused sort + phase-locked gather + tail convW.
// Blocks 0..1023 (dispatched FIRST, all co-resident at 4/CU): XCD x=b&7
// owns table x>>1, bm-half x&1; wave wv sorts and sweeps units u=wv+8i.
// Prologue: per-unit 64-lane bitonic sort of keys idx*64+l into LDS +
// per-chunk histogram. Sweep: 8 vocab chunks (~3.2 MB window, fits per-XCD
// L2; r12 measured 88% L2 absorption at this structure), acc/cursors in
// registers, inner loop unrolled x2 per subgroup -> 4 rows in flight/wave.
// Blocks 1024.. fill CUs as gather drains: W -> Wt fp16 transpose.
// -------------------------------------------------------------------------
__global__ __launch_bounds__(512, 8) void k_gather_all(
        const int* __restrict__ xe, const float* __restrict__ emb,
        const float* __restrict__ W, float* __restrict__ Mw,
        _Float16* __restrict__ Wt) {
    const int t = threadIdx.x;

    __shared__ unsigned      skeys[UPB][PL];    // 10 KB
    __shared__ unsigned char scnt[UPB][NCH];    // 0.4 KB
    __shared__ float         ls[PD][36];        // 18.4 KB (convW branch)

    if (blockIdx.x >= NGB) {
        // ---- convW: 128 cols per block, 4 passes of 32 cols ----
        const int cb = (blockIdx.x - NGB) * 128;
        #pragma unroll 1
        for (int p = 0; p < 4; ++p) {
            const int c0 = cb + p * 32;
            #pragma unroll
            for (int i = 0; i < 2; ++i) {
                const int e  = t + i * 512;      // 1024 chunks = 128 k x 8
                const int kk = e >> 3, c4 = (e & 7) * 4;
                const int gc = c0 + c4;
                f32x4 v;
                if (gc + 3 < PV) {
                    v = *reinterpret_cast<const f32x4*>(W + (size_t)kk * PV + gc);
                } else {
                    v.x = (gc + 0 < PV) ? W[(size_t)kk * PV + gc + 0] : 0.f;
                    v.y = (gc + 1 < PV) ? W[(size_t)kk * PV + gc + 1] : 0.f;
                    v.z = (gc + 2 < PV) ? W[(size_t)kk * PV + gc + 2] : 0.f;
                    v.w = (gc + 3 < PV) ? W[(size_t)kk * PV + gc + 3] : 0.f;
                }
                *reinterpret_cast<f32x4*>(&ls[kk][c4]) = v;
            }
            __syncthreads();
            {
                const int c = t >> 4, k0 = (t & 15) * 8;
                f16x8 v;
                #pragma unroll
                for (int j = 0; j < 8; ++j) v[j] = (_Float16)ls[k0 + j][c];
                *reinterpret_cast<f16x8*>(Wt + (size_t)(c0 + c) * PD + k0) = v;
            }
            __syncthreads();
        }
        return;
    }

    // ---- gather ----
    const int b    = blockIdx.x;
    const int x    = b & 7;
    const int k    = x >> 1;
    const int half = x & 1;
    const int slot = b >> 3;             // 0..127
    const int bm0  = half * 6400 + slot * UPB;

    const int wv   = t >> 6;             // 0..7
    const int lane = t & 63;
    const int sub  = lane >> 5;          // subgroup 0/1
    const int d4   = (lane & 31) * 4;

    // prologue: sort + histogram for this wave's own units (no cross-wave use)
    for (int u = wv; u < UPB; u += 8) {
        const int bm = bm0 + u;
        unsigned key = 0xFFFFFFFFu;
        if (lane < PL)
            key = ((unsigned)xe[(size_t)bm * PL + lane] << 6) | (unsigned)lane;
        #pragma unroll
        for (int kk = 2; kk <= 64; kk <<= 1) {
            #pragma unroll
            for (int j = kk >> 1; j > 0; j >>= 1) {
                const unsigned other = (unsigned)__shfl_xor((int)key, j);
                const bool up      = ((lane & kk) == 0);
                const bool keepMin = (((lane & j) == 0) == up);
                const unsigned mn = key < other ? key : other;
                const unsigned mx = key < other ? other : key;
                key = keepMin ? mn : mx;
            }
        }
        if (lane < PL) skeys[u][lane] = key;
        const int ci = (int)((key >> 6) / (unsigned)CHW);
        #pragma unroll
        for (int c = 0; c < NCH; ++c) {
            const unsigned long long m = __ballot(lane < PL && ci == c);
            if (lane == c) scnt[u][c] = (unsigned char)__popcll(m);
        }
    }
    __syncthreads();

    const float* tab = emb + (size_t)k * TS;
    const float dd0 = (float)(d4 + 0) - 63.0f;
    const float dd1 = (float)(d4 + 1) - 63.0f;
    const float dd2 = (float)(d4 + 2) - 63.0f;
    const float dd3 = (float)(d4 + 3) - 63.0f;

    f32x4 acc[7];
    int   cur[7];
    #pragma unroll
    for (int i = 0; i < 7; ++i) {
        acc[i] = (f32x4){0.f, 0.f, 0.f, 0.f};
        cur[i] = 0;
    }

    #pragma unroll 1
    for (int c = 0; c < NCH; ++c) {
        #pragma unroll
        for (int i = 0; i < 7; ++i) {
            const int u = wv + 8 * i;
            if (u < UPB) {
                const int n    = (int)scnt[u][c];
                const int base = cur[i];
                f32x4 a = acc[i];
                int j = sub;
                // pairwise unroll within parity class: 2 loads in flight
                for (; j + 2 < n; j += 4) {
                    const unsigned k1 = skeys[u][base + j];
                    const unsigned k2 = skeys[u][base + j + 2];
                    const f32x4 v1 = *reinterpret_cast<const f32x4*>(
                        tab + (size_t)(k1 >> 6) * PD + d4);
                    const f32x4 v2 = *reinterpret_cast<const f32x4*>(
                        tab + (size_t)(k2 >> 6) * PD + d4);
                    const float fl1 = PEC * ((float)(int)(k1 & 63u) - 24.0f);
                    const float fl2 = PEC * ((float)(int)(k2 & 63u) - 24.0f);
                    a.x += (1.0f + fl1 * dd0) * v1.x + (1.0f + fl2 * dd0) * v2.x;
                    a.y += (1.0f + fl1 * dd1) * v1.y + (1.0f + fl2 * dd1) * v2.y;
                    a.z += (1.0f + fl1 * dd2) * v1.z + (1.0f + fl2 * dd2) * v2.z;
                    a.w += (1.0f + fl1 * dd3) * v1.w + (1.0f + fl2 * dd3) * v2.w;
                }
                if (j < n) {
                    const unsigned k1 = skeys[u][base + j];
                    const f32x4 v1 = *reinterpret_cast<const f32x4*>(
                        tab + (size_t)(k1 >> 6) * PD + d4);
                    const float fl1 = PEC * ((float)(int)(k1 & 63u) - 24.0f);
                    a.x += (1.0f + fl1 * dd0) * v1.x;
                    a.y += (1.0f + fl1 * dd1) * v1.y;
                    a.z += (1.0f + fl1 * dd2) * v1.z;
                    a.w += (1.0f + fl1 * dd3) * v1.w;
                }
                acc[i] = a;
                cur[i] = base + n;
            }
        }
    }

    // merge subgroup 1 into subgroup 0, store 512B rows
    #pragma unroll
    for (int i = 0; i < 7; ++i) {
        const int u = wv + 8 * i;
        f32x4 o;
        o.x = __shfl_down(acc[i].x, 32);
        o.y = __shfl_down(acc[i].y, 32);
        o.z = __shfl_down(acc[i].z, 32);
        o.w = __shfl_down(acc[i].w, 32);
        if (u < UPB && sub == 0) {
            const f32x4 s = acc[i] + o;
            *reinterpret_cast<f32x4*>(
                Mw + ((size_t)k * PBM + bm0 + u) * PD + d4) = s;
        }
    }
}

// -------------------------------------------------------------------------
// Kernel 2: per-b u + 3 hops. 256 blocks x 1024 threads (proven r10).
// -------------------------------------------------------------------------
__global__ __launch_bounds__(1024) void k_hops(const int* __restrict__ xq,
                                               const float* __restrict__ emb,
                                               const float* __restrict__ Mw,
                                               _Float16* __restrict__ uh) {
    const int b = blockIdx.x;
    const int t = threadIdx.x;
    const int g = t >> 7;
    const int d = t & 127;

    __shared__ float us[PD];
    __shared__ float ps[64];
    __shared__ float red[8][PD];
    __shared__ int   sidx[PL];

    if (t < PL) sidx[t] = xq[(size_t)b * PL + t];
    __syncthreads();

    {
        const float dd = (float)d - 63.0f;
        float acc = 0.f;
        for (int l = g; l < PL; l += 8)
            acc += (1.0f + PEC * dd * ((float)l - 24.0f)) *
                   emb[(size_t)sidx[l] * PD + d];
        red[g][d] = acc;
    }
    __syncthreads();
    if (t < PD) {
        float s = red[0][t];
        #pragma unroll
        for (int i = 1; i < 8; ++i) s += red[i][t];
        us[t] = s;
    }
    __syncthreads();

    const int lane = t & 63;
    const int wave = t >> 6;

    for (int hop = 0; hop < 3; ++hop) {
        const float* Ma = Mw + ((size_t)hop * PBM + (size_t)b * PM) * PD;
        const float* Mc = Ma + (size_t)PBM * PD;

        for (int m = wave; m < PM; m += 16) {
            const float* row = Ma + (size_t)m * PD;
            float part = row[lane] * us[lane] + row[lane + 64] * us[lane + 64];
            #pragma unroll
            for (int off = 32; off > 0; off >>= 1)
                part += __shfl_down(part, off);
            if (lane == 0) ps[m] = part;
        }
        __syncthreads();

        if (wave == 0) {
            float s = (lane < PM) ? ps[lane] : -INFINITY;
            float mx = s;
            #pragma unroll
            for (int off = 32; off > 0; off >>= 1)
                mx = fmaxf(mx, __shfl_xor(mx, off));
            float e = (lane < PM) ? __expf(s - mx) : 0.f;
            float sm = e;
            #pragma unroll
            for (int off = 32; off > 0; off >>= 1)
                sm += __shfl_xor(sm, off);
            if (lane < PM) ps[lane] = e / sm;
        }
        __syncthreads();

        {
            float o = 0.f;
            for (int m = g; m < PM; m += 8)
                o += ps[m] * Mc[(size_t)m * PD + d];
            red[g][d] = o;
        }
        __syncthreads();
        if (t < PD) {
            float s = red[0][t];
            #pragma unroll
            for (int i = 1; i < 8; ++i) s += red[i][t];
            us[t] += s;
        }
        __syncthreads();
    }

    if (t < PD) uh[(size_t)b * PD + t] = (_Float16)us[t];
}

// -------------------------------------------------------------------------
// Kernel 3: GEMM pass — E = exp(v - tile_max) fp16 (LDS-staged, coalesced
// f16x8 stores), (mx,se) to part. grid (786,2), 128 thr. (proven r10)
// -------------------------------------------------------------------------
__global__ __launch_bounds__(128) void k_gemm_exp(const _Float16* __restrict__ uh,
                                                  const _Float16* __restrict__ Wt,
                                                  _Float16* __restrict__ Eh,
                                                  float* __restrict__ part) {
    const int tile    = blockIdx.x;
    const int colBase = tile * 64;
    const int w       = threadIdx.x >> 6;
    const int l       = threadIdx.x & 63;
    const int lrow    = l & 15;
    const int lk      = (l >> 4) * 8;
    const int rb0     = blockIdx.y * 128;
    const int rowBase = rb0 + w * 64;

    __shared__ _Float16 es[128][72];

    f32x4 acc[4][4];
    #pragma unroll
    for (int i = 0; i < 4; ++i)
        #pragma unroll
        for (int j = 0; j < 4; ++j)
            acc[i][j] = (f32x4){0.f, 0.f, 0.f, 0.f};

    #pragma unroll
    for (int ks = 0; ks < 4; ++ks) {
        const int k0 = ks * 32 + lk;
        f16x8 a[4], bfr[4];
        #pragma unroll
        for (int mi = 0; mi < 4; ++mi)
            a[mi] = *reinterpret_cast<const f16x8*>(
                uh + (size_t)(rowBase + mi * 16 + lrow) * PD + k0);
        #pragma unroll
        for (int ni = 0; ni < 4; ++ni)
            bfr[ni] = *reinterpret_cast<const f16x8*>(
                Wt + (size_t)(colBase + ni * 16 + lrow) * PD + k0);
        #pragma unroll
        for (int mi = 0; mi < 4; ++mi)
            #pragma unroll
            for (int ni = 0; ni < 4; ++ni)
                acc[mi][ni] = __builtin_amdgcn_mfma_f32_16x16x32_f16(
                    a[mi], bfr[ni], acc[mi][ni], 0, 0, 0);
    }

    const int rquad = (l >> 4) * 4;
    #pragma unroll
    for (int mi = 0; mi < 4; ++mi) {
        #pragma unroll
        for (int q = 0; q < 4; ++q) {
            const int row   = rowBase + mi * 16 + rquad + q;
            const int row_l = row - rb0;
            float v[4];
            float mx = -INFINITY;
            #pragma unroll
            for (int j = 0; j < 4; ++j) {
                const int col = colBase + j * 16 + lrow;
                v[j] = (col < PV) ? acc[mi][j][q] : -INFINITY;
                mx = fmaxf(mx, v[j]);
            }
            #pragma unroll
            for (int msk = 1; msk < 16; msk <<= 1)
                mx = fmaxf(mx, __shfl_xor(mx, msk));
            float se = 0.f;
            #pragma unroll
            for (int j = 0; j < 4; ++j) {
                const float e = __expf(v[j] - mx);
                se += e;
                es[row_l][j * 16 + lrow] = (_Float16)e;
            }
            #pragma unroll
            for (int msk = 1; msk < 16; msk <<= 1)
                se += __shfl_xor(se, msk);
            if (lrow == 0) {
                part[((size_t)tile * PB + row) * 2 + 0] = mx;
                part[((size_t)tile * PB + row) * 2 + 1] = se;
            }
        }
    }
    __syncthreads();

    #pragma unroll
    for (int i = 0; i < 8; ++i) {
        const int ch    = threadIdx.x + i * 128;
        const int row_l = ch >> 3, cq = ch & 7;
        const f16x8 v = *reinterpret_cast<const f16x8*>(&es[row_l][cq * 8]);
        *reinterpret_cast<f16x8*>(
            Eh + (size_t)(rb0 + row_l) * PVP + colBase + cq * 8) = v;
    }
}

// -------------------------------------------------------------------------
// Kernel 4: fused merge + scale (proven r10).
// -------------------------------------------------------------------------
__global__ __launch_bounds__(512) void k_scale(const _Float16* __restrict__ Eh,
                                               const float* __restrict__ part,
                                               float* __restrict__ out) {
    const int b = blockIdx.x;
    const int t = threadIdx.x;
    __shared__ float sc[NT];
    __shared__ float wm[8], ws[8];

    float M = -INFINITY, S = 0.f;
    for (int tile = t; tile < NT; tile += 512) {
        const float m = part[((size_t)tile * PB + b) * 2 + 0];
        const float s = part[((size_t)tile * PB + b) * 2 + 1];
        const float nM = fmaxf(M, m);
        S = S * __expf(M - nM) + s * __expf(m - nM);
        M = nM;
    }
    #pragma unroll
    for (int off = 32; off > 0; off >>= 1) {
        const float m2 = __shfl_xor(M, off);
        const float s2 = __shfl_xor(S, off);
        const float nM = fmaxf(M, m2);
        S = S * __expf(M - nM) + s2 * __expf(m2 - nM);
        M = nM;
    }
    if ((t & 63) == 0) { wm[t >> 6] = M; ws[t >> 6] = S; }
    __syncthreads();
    M = -INFINITY; S = 0.f;
    #pragma unroll
    for (int i = 0; i < 8; ++i) {
        const float m = wm[i], s = ws[i];
        const float nM = fmaxf(M, m);
        S = S * __expf(M - nM) + s * __expf(m - nM);
        M = nM;
    }
    const float rinv = 1.0f / S;

    for (int tile = t; tile < NT; tile += 512)
        sc[tile] = __expf(part[((size_t)tile * PB + b) * 2 + 0] - M) * rinv;
    __syncthreads();

    const _Float16* erow = Eh + (size_t)b * PVP;
    float*          orow = out + (size_t)b * PV;

    const int NP = PV >> 1;
    for (int i = t; i < NP; i += 512) {
        const int c = 2 * i;
        const unsigned u = *reinterpret_cast<const unsigned*>(erow + c);
        const _Float16 e0 = ((const _Float16*)&u)[0];
        const _Float16 e1 = ((const _Float16*)&u)[1];
        const float s0 = sc[c >> 6];
        orow[c]     = (float)e0 * s0;
        orow[c + 1] = (float)e1 * s0;
    }
    if (t == 0)
        orow[PV - 1] = (float)erow[PV - 1] * sc[(PV - 1) >> 6];
}

// -------------------------------------------------------------------------
extern "C" void kernel_launch(void* const* d_in, const int* in_sizes, int n_in,
                              void* d_out, int out_size, void* d_ws, size_t ws_size,
                              hipStream_t stream) {
    const int*   x_e = (const int*)d_in[0];    // [B, M, L]
    const int*   x_q = (const int*)d_in[1];    // [B, L]
    const float* emb = (const float*)d_in[2];  // [4, V, D]
    const float* W   = (const float*)d_in[3];  // [D, V]
    float*       out = (float*)d_out;          // [B, V]
    (void)n_in; (void)in_sizes; (void)out_size; (void)ws_size;

    char* p = (char*)d_ws;
    float*    M_ws = (float*)p;                p += (size_t)4 * PBM * PD * 4;   // 26.2 MB
    _Float16* uh   = (_Float16*)p;             p += (size_t)PB * PD * 2;        // 64 KB
    _Float16* Wt   = (_Float16*)p;             p += (size_t)PVP * PD * 2;       // 12.9 MB
    float*    part = (float*)p;                p += (size_t)NT * PB * 2 * 4;    // 1.6 MB
    _Float16* Eh   = (_Float16*)p;             // 256*50304*2 = 25.8 MB

    k_gather_all<<<dim3(NGB + NCV), dim3(512),  0, stream>>>(
        x_e, emb, W, M_ws, Wt);
    k_hops    <<<dim3(PB),    dim3(1024), 0, stream>>>(x_q, emb, M_ws, uh);
    k_gemm_exp<<<dim3(NT, 2), dim3(128),  0, stream>>>(uh, Wt, Eh, part);
    k_scale   <<<dim3(PB),    dim3(512),  0, stream>>>(Eh, part, out);
}

// Round 14
// 224.945 us; speedup vs baseline: 1.0971x; 1.0971x over previous
//
#include <hip/hip_runtime.h>
#include <hip/hip_bf16.h>
#include <hip/hip_fp16.h>
#include <math.h>

// Problem constants (MemN2N): B=256, M=50, L=50, V=50257, D=128, HOPS=3
#define PB   256
#define PM   50
#define PL   50
#define PV   50257
#define PD   128
#define PBM  (PB * PM)              // 12800
#define TS   ((size_t)PV * PD)      // one embedding table, elements
#define PEC  0.000625f              // 4/(D*L) = 4/6400
#define NT   786                    // ceil(PV/64) column tiles
#define PVP  (NT * 64)              // 50304 padded vocab
#define NCONV 786                   // convW blocks at front of sortconv launch
#define NCH  16                     // vocab chunks (~1.6 MB window/table)
#define CHW  3142                   // ceil(PV/NCH)
#define UPB  50                     // bm units per gather block

typedef _Float16 f16x8 __attribute__((ext_vector_type(8)));
typedef float    f32x4 __attribute__((ext_vector_type(4)));

// -------------------------------------------------------------------------
// Kernel 0 (fused): blocks 0..785 transpose W -> Wt fp16; rest: per-bm
// 64-lane bitonic sort of keys idx*64+l, plus per-chunk count histogram.
// (r12 proven)
// -------------------------------------------------------------------------
__global__ __launch_bounds__(256) void k_sortconv(const int* __restrict__ xe,
                                                  const float* __restrict__ W,
                                                  unsigned* __restrict__ skey,
                                                  unsigned char* __restrict__ ucnt,
                                                  _Float16* __restrict__ Wt) {
    const int t = threadIdx.x;

    if (blockIdx.x < NCONV) {
        __shared__ float ls[PD][20];
        const bool edge = (blockIdx.x == NCONV - 1);
        #pragma unroll 1
        for (int p = 0; p < 4; ++p) {
            const int c0 = blockIdx.x * 64 + p * 16;
            #pragma unroll
            for (int i = 0; i < 2; ++i) {
                const int e  = t + i * 256;
                const int kk = e >> 2, c4 = (e & 3) * 4;
                const int gc = c0 + c4;
                f32x4 v;
                if (!edge || gc + 3 < PV) {
                    v = *reinterpret_cast<const f32x4*>(W + (size_t)kk * PV + gc);
                } else {
                    v.x = (gc + 0 < PV) ? W[(size_t)kk * PV + gc + 0] : 0.f;
                    v.y = (gc + 1 < PV) ? W[(size_t)kk * PV + gc + 1] : 0.f;
                    v.z = (gc + 2 < PV) ? W[(size_t)kk * PV + gc + 2] : 0.f;
                    v.w = (gc + 3 < PV) ? W[(size_t)kk * PV + gc + 3] : 0.f;
                }
                *reinterpret_cast<f32x4*>(&ls[kk][c4]) = v;
            }
            __syncthreads();
            {
                const int c = t >> 4, k0 = (t & 15) * 8;
                f16x8 v;
                #pragma unroll
                for (int j = 0; j < 8; ++j) v[j] = (_Float16)ls[k0 + j][c];
                *reinterpret_cast<f16x8*>(Wt + (size_t)(c0 + c) * PD + k0) = v;
            }
            __syncthreads();
        }
        return;
    }

    // ---- bitonic sort + chunk histogram: one wave per bm ----
    const int wv   = t >> 6;
    const int lane = t & 63;
    const int bm   = (blockIdx.x - NCONV) * 4 + wv;

    unsigned key = 0xFFFFFFFFu;
    if (lane < PL)
        key = ((unsigned)xe[(size_t)bm * PL + lane] << 6) | (unsigned)lane;

    #pragma unroll
    for (int k = 2; k <= 64; k <<= 1) {
        #pragma unroll
        for (int j = k >> 1; j > 0; j >>= 1) {
            const unsigned other = (unsigned)__shfl_xor((int)key, j);
            const bool up      = ((lane & k) == 0);
            const bool keepMin = (((lane & j) == 0) == up);
            const unsigned mn = key < other ? key : other;
            const unsigned mx = key < other ? other : key;
            key = keepMin ? mn : mx;
        }
    }
    if (lane < PL) skey[(size_t)bm * PL + lane] = key;

    const int ci = (int)((key >> 6) / (unsigned)CHW);
    #pragma unroll
    for (int c = 0; c < NCH; ++c) {
        const unsigned long long m = __ballot(lane < PL && ci == c);
        if (lane == c) ucnt[bm * NCH + c] = (unsigned char)__popcll(m);
    }
}

// -------------------------------------------------------------------------
// Kernel 1: phase-locked persistent gather v3 (r12 + paired-unit MLP).
// 1024 blocks x 512 thr (4/CU, all co-resident). XCD x=b&7 owns table
// x>>1, bm-half x&1. 16-chunk vocab sweep (1.6 MB window, 88% L2-absorb
// measured r12). NEW: units processed in compile-time pairs (0,1),(2,3),
// (4,5) — both units' row loads issued before either's FMAs, branchless
// via weight-zeroing -> 4 rows in flight/wave (r12 had 2). Unit 6 single.
// -------------------------------------------------------------------------
__global__ __launch_bounds__(512, 8) void k_gatherp(
        const unsigned* __restrict__ skey,
        const unsigned char* __restrict__ ucnt,
        const float* __restrict__ emb,
        float* __restrict__ Mw) {
    const int b    = blockIdx.x;         // 0..1023
    const int x    = b & 7;              // XCD
    const int k    = x >> 1;             // table 0..3
    const int half = x & 1;
    const int slot = b >> 3;             // 0..127
    const int bm0  = half * 6400 + slot * UPB;

    const int t    = threadIdx.x;
    const int wv   = t >> 6;             // wave 0..7
    const int lane = t & 63;
    const int sub  = lane >> 5;          // subgroup 0/1
    const int d4   = (lane & 31) * 4;

    __shared__ unsigned      skeys[UPB][PL];    // 10 KB
    __shared__ unsigned char scnt[UPB][NCH];    // 0.8 KB

    for (int i = t; i < UPB * PL; i += 512)
        ((unsigned*)skeys)[i] = skey[(size_t)bm0 * PL + i];
    if (t < UPB * NCH / 4)
        ((unsigned*)scnt)[t] = ((const unsigned*)(ucnt + bm0 * NCH))[t];
    __syncthreads();

    const float* tab = emb + (size_t)k * TS;
    const float dd0 = (float)(d4 + 0) - 63.0f;
    const float dd1 = (float)(d4 + 1) - 63.0f;
    const float dd2 = (float)(d4 + 2) - 63.0f;
    const float dd3 = (float)(d4 + 3) - 63.0f;

    // wave wv owns units u = wv + 8*i (i < 7; u<48 for i<6, unit 6 if wv<2)
    f32x4 acc[7];
    int   cur[7];
    #pragma unroll
    for (int i = 0; i < 7; ++i) {
        acc[i] = (f32x4){0.f, 0.f, 0.f, 0.f};
        cur[i] = 0;
    }

    #pragma unroll 1
    for (int c = 0; c < NCH; ++c) {
        // paired units (0,1),(2,3),(4,5): 4 rows in flight per wave
        #pragma unroll
        for (int pi = 0; pi < 3; ++pi) {
            const int iA = 2 * pi, iB = iA + 1;
            const int uA = wv + 8 * iA;          // <= 39 < UPB always
            const int uB = wv + 8 * iB;          // <= 47 < UPB always
            const int nA = (int)scnt[uA][c];
            const int nB = (int)scnt[uB][c];
            const int bA = cur[iA], bB = cur[iB];
            f32x4 aA = acc[iA], aB = acc[iB];
            const int nmax = nA > nB ? nA : nB;
            for (int j = sub; j < nmax; j += 2) {
                const bool dA = (j < nA), dB = (j < nB);
                const unsigned kA = skeys[uA][dA ? bA + j : 0];
                const unsigned kB = skeys[uB][dB ? bB + j : 0];
                const f32x4 vA = *reinterpret_cast<const f32x4*>(
                    tab + (size_t)(kA >> 6) * PD + d4);
                const f32x4 vB = *reinterpret_cast<const f32x4*>(
                    tab + (size_t)(kB >> 6) * PD + d4);
                const float pA = dA ? 1.0f : 0.0f;
                const float pB = dB ? 1.0f : 0.0f;
                const float fA = pA * (PEC * ((float)(int)(kA & 63u) - 24.0f));
                const float fB = pB * (PEC * ((float)(int)(kB & 63u) - 24.0f));
                aA.x += (pA + fA * dd0) * vA.x;
                aA.y += (pA + fA * dd1) * vA.y;
                aA.z += (pA + fA * dd2) * vA.z;
                aA.w += (pA + fA * dd3) * vA.w;
                aB.x += (pB + fB * dd0) * vB.x;
                aB.y += (pB + fB * dd1) * vB.y;
                aB.z += (pB + fB * dd2) * vB.z;
                aB.w += (pB + fB * dd3) * vB.w;
            }
            acc[iA] = aA; acc[iB] = aB;
            cur[iA] = bA + nA; cur[iB] = bB + nB;
        }
        // single unit 6 (only waves 0,1): old 2-in-flight parity loop
        {
            const int u = wv + 48;
            if (u < UPB) {
                const int n    = (int)scnt[u][c];
                const int base = cur[6];
                f32x4 a = acc[6];
                for (int j = sub; j < n; j += 2) {
                    const unsigned k1 = skeys[u][base + j];
                    const f32x4 v1 = *reinterpret_cast<const f32x4*>(
                        tab + (size_t)(k1 >> 6) * PD + d4);
                    const float fl = PEC * ((float)(int)(k1 & 63u) - 24.0f);
                    a.x += (1.0f + fl * dd0) * v1.x;
                    a.y += (1.0f + fl * dd1) * v1.y;
                    a.z += (1.0f + fl * dd2) * v1.z;
                    a.w += (1.0f + fl * dd3) * v1.w;
                }
                acc[6] = a;
                cur[6] = base + n;
            }
        }
    }

    // merge subgroup 1 into subgroup 0, store 512B rows
    #pragma unroll
    for (int i = 0; i < 7; ++i) {
        const int u = wv + 8 * i;
        f32x4 o;
        o.x = __shfl_down(acc[i].x, 32);
        o.y = __shfl_down(acc[i].y, 32);
        o.z = __shfl_down(acc[i].z, 32);
        o.w = __shfl_down(acc[i].w, 32);
        if (u < UPB && sub == 0) {
            const f32x4 s = acc[i] + o;
            *reinterpret_cast<f32x4*>(
                Mw + ((size_t)k * PBM + bm0 + u) * PD + d4) = s;
        }
    }
}

// -------------------------------------------------------------------------
// Kernel 2: per-b u + 3 hops. 256 blocks x 1024 threads (proven r10).
// -------------------------------------------------------------------------
__global__ __launch_bounds__(1024) void k_hops(const int* __restrict__ xq,
                                               const float* __restrict__ emb,
                                               const float* __restrict__ Mw,
                                               _Float16* __restrict__ uh) {
    const int b = blockIdx.x;
    const int t = threadIdx.x;
    const int g = t >> 7;
    const int d = t & 127;

    __shared__ float us[PD];
    __shared__ float ps[64];
    __shared__ float red[8][PD];
    __shared__ int   sidx[PL];

    if (t < PL) sidx[t] = xq[(size_t)b * PL + t];
    __syncthreads();

    {
        const float dd = (float)d - 63.0f;
        float acc = 0.f;
        for (int l = g; l < PL; l += 8)
            acc += (1.0f + PEC * dd * ((float)l - 24.0f)) *
                   emb[(size_t)sidx[l] * PD + d];
        red[g][d] = acc;
    }
    __syncthreads();
    if (t < PD) {
        float s = red[0][t];
        #pragma unroll
        for (int i = 1; i < 8; ++i) s += red[i][t];
        us[t] = s;
    }
    __syncthreads();

    const int lane = t & 63;
    const int wave = t >> 6;

    for (int hop = 0; hop < 3; ++hop) {
        const float* Ma = Mw + ((size_t)hop * PBM + (size_t)b * PM) * PD;
        const float* Mc = Ma + (size_t)PBM * PD;

        for (int m = wave; m < PM; m += 16) {
            const float* row = Ma + (size_t)m * PD;
            float part = row[lane] * us[lane] + row[lane + 64] * us[lane + 64];
            #pragma unroll
            for (int off = 32; off > 0; off >>= 1)
                part += __shfl_down(part, off);
            if (lane == 0) ps[m] = part;
        }
        __syncthreads();

        if (wave == 0) {
            float s = (lane < PM) ? ps[lane] : -INFINITY;
            float mx = s;
            #pragma unroll
            for (int off = 32; off > 0; off >>= 1)
                mx = fmaxf(mx, __shfl_xor(mx, off));
            float e = (lane < PM) ? __expf(s - mx) : 0.f;
            float sm = e;
            #pragma unroll
            for (int off = 32; off > 0; off >>= 1)
                sm += __shfl_xor(sm, off);
            if (lane < PM) ps[lane] = e / sm;
        }
        __syncthreads();

        {
            float o = 0.f;
            for (int m = g; m < PM; m += 8)
                o += ps[m] * Mc[(size_t)m * PD + d];
            red[g][d] = o;
        }
        __syncthreads();
        if (t < PD) {
            float s = red[0][t];
            #pragma unroll
            for (int i = 1; i < 8; ++i) s += red[i][t];
            us[t] += s;
        }
        __syncthreads();
    }

    if (t < PD) uh[(size_t)b * PD + t] = (_Float16)us[t];
}

// -------------------------------------------------------------------------
// Kernel 3: GEMM pass — E = exp(v - tile_max) fp16 (LDS-staged, coalesced
// f16x8 stores), (mx,se) to part. grid (786,2), 128 thr. (proven r10)
// -------------------------------------------------------------------------
__global__ __launch_bounds__(128) void k_gemm_exp(const _Float16* __restrict__ uh,
                                                  const _Float16* __restrict__ Wt,
                                                  _Float16* __restrict__ Eh,
                                                  float* __restrict__ part) {
    const int tile    = blockIdx.x;
    const int colBase = tile * 64;
    const int w       = threadIdx.x >> 6;
    const int l       = threadIdx.x & 63;
    const int lrow    = l & 15;
    const int lk      = (l >> 4) * 8;
    const int rb0     = blockIdx.y * 128;
    const int rowBase = rb0 + w * 64;

    __shared__ _Float16 es[128][72];

    f32x4 acc[4][4];
    #pragma unroll
    for (int i = 0; i < 4; ++i)
        #pragma unroll
        for (int j = 0; j < 4; ++j)
            acc[i][j] = (f32x4){0.f, 0.f, 0.f, 0.f};

    #pragma unroll
    for (int ks = 0; ks < 4; ++ks) {
        const int k0 = ks * 32 + lk;
        f16x8 a[4], bfr[4];
        #pragma unroll
        for (int mi = 0; mi < 4; ++mi)
            a[mi] = *reinterpret_cast<const f16x8*>(
                uh + (size_t)(rowBase + mi * 16 + lrow) * PD + k0);
        #pragma unroll
        for (int ni = 0; ni < 4; ++ni)
            bfr[ni] = *reinterpret_cast<const f16x8*>(
                Wt + (size_t)(colBase + ni * 16 + lrow) * PD + k0);
        #pragma unroll
        for (int mi = 0; mi < 4; ++mi)
            #pragma unroll
            for (int ni = 0; ni < 4; ++ni)
                acc[mi][ni] = __builtin_amdgcn_mfma_f32_16x16x32_f16(
                    a[mi], bfr[ni], acc[mi][ni], 0, 0, 0);
    }

    const int rquad = (l >> 4) * 4;
    #pragma unroll
    for (int mi = 0; mi < 4; ++mi) {
        #pragma unroll
        for (int q = 0; q < 4; ++q) {
            const int row   = rowBase + mi * 16 + rquad + q;
            const int row_l = row - rb0;
            float v[4];
            float mx = -INFINITY;
            #pragma unroll
            for (int j = 0; j < 4; ++j) {
                const int col = colBase + j * 16 + lrow;
                v[j] = (col < PV) ? acc[mi][j][q] : -INFINITY;
                mx = fmaxf(mx, v[j]);
            }
            #pragma unroll
            for (int msk = 1; msk < 16; msk <<= 1)
                mx = fmaxf(mx, __shfl_xor(mx, msk));
            float se = 0.f;
            #pragma unroll
            for (int j = 0; j < 4; ++j) {
                const float e = __expf(v[j] - mx);
                se += e;
                es[row_l][j * 16 + lrow] = (_Float16)e;
            }
            #pragma unroll
            for (int msk = 1; msk < 16; msk <<= 1)
                se += __shfl_xor(se, msk);
            if (lrow == 0) {
                part[((size_t)tile * PB + row) * 2 + 0] = mx;
                part[((size_t)tile * PB + row) * 2 + 1] = se;
            }
        }
    }
    __syncthreads();

    #pragma unroll
    for (int i = 0; i < 8; ++i) {
        const int ch    = threadIdx.x + i * 128;
        const int row_l = ch >> 3, cq = ch & 7;
        const f16x8 v = *reinterpret_cast<const f16x8*>(&es[row_l][cq * 8]);
        *reinterpret_cast<f16x8*>(
            Eh + (size_t)(rb0 + row_l) * PVP + colBase + cq * 8) = v;
    }
}

// -------------------------------------------------------------------------
// Kernel 4: fused merge + scale (proven r10).
// -------------------------------------------------------------------------
__global__ __launch_bounds__(512) void k_scale(const _Float16* __restrict__ Eh,
                                               const float* __restrict__ part,
                                               float* __restrict__ out) {
    const int b = blockIdx.x;
    const int t = threadIdx.x;
    __shared__ float sc[NT];
    __shared__ float wm[8], ws[8];

    float M = -INFINITY, S = 0.f;
    for (int tile = t; tile < NT; tile += 512) {
        const float m = part[((size_t)tile * PB + b) * 2 + 0];
        const float s = part[((size_t)tile * PB + b) * 2 + 1];
        const float nM = fmaxf(M, m);
        S = S * __expf(M - nM) + s * __expf(m - nM);
        M = nM;
    }
    #pragma unroll
    for (int off = 32; off > 0; off >>= 1) {
        const float m2 = __shfl_xor(M, off);
        const float s2 = __shfl_xor(S, off);
        const float nM = fmaxf(M, m2);
        S = S * __expf(M - nM) + s2 * __expf(m2 - nM);
        M = nM;
    }
    if ((t & 63) == 0) { wm[t >> 6] = M; ws[t >> 6] = S; }
    __syncthreads();
    M = -INFINITY; S = 0.f;
    #pragma unroll
    for (int i = 0; i < 8; ++i) {
        const float m = wm[i], s = ws[i];
        const float nM = fmaxf(M, m);
        S = S * __expf(M - nM) + s * __expf(m - nM);
        M = nM;
    }
    const float rinv = 1.0f / S;

    for (int tile = t; tile < NT; tile += 512)
        sc[tile] = __expf(part[((size_t)tile * PB + b) * 2 + 0] - M) * rinv;
    __syncthreads();

    const _Float16* erow = Eh + (size_t)b * PVP;
    float*          orow = out + (size_t)b * PV;

    const int NP = PV >> 1;
    for (int i = t; i < NP; i += 512) {
        const int c = 2 * i;
        const unsigned u = *reinterpret_cast<const unsigned*>(erow + c);
        const _Float16 e0 = ((const _Float16*)&u)[0];
        const _Float16 e1 = ((const _Float16*)&u)[1];
        const float s0 = sc[c >> 6];
        orow[c]     = (float)e0 * s0;
        orow[c + 1] = (float)e1 * s0;
    }
    if (t == 0)
        orow[PV - 1] = (float)erow[PV - 1] * sc[(PV - 1) >> 6];
}

// -------------------------------------------------------------------------
extern "C" void kernel_launch(void* const* d_in, const int* in_sizes, int n_in,
                              void* d_out, int out_size, void* d_ws, size_t ws_size,
                              hipStream_t stream) {
    const int*   x_e = (const int*)d_in[0];    // [B, M, L]
    const int*   x_q = (const int*)d_in[1];    // [B, L]
    const float* emb = (const float*)d_in[2];  // [4, V, D]
    const float* W   = (const float*)d_in[3];  // [D, V]
    float*       out = (float*)d_out;          // [B, V]
    (void)n_in; (void)in_sizes; (void)out_size; (void)ws_size;

    char* p = (char*)d_ws;
    float*         M_ws = (float*)p;           p += (size_t)4 * PBM * PD * 4;   // 26.2 MB
    _Float16*      uh   = (_Float16*)p;        p += (size_t)PB * PD * 2;        // 64 KB
    _Float16*      Wt   = (_Float16*)p;        p += (size_t)PVP * PD * 2;       // 12.9 MB
    float*         part = (float*)p;           p += (size_t)NT * PB * 2 * 4;    // 1.6 MB
    _Float16*      Eh   = (_Float16*)p;        p += (size_t)PB * PVP * 2;       // 25.8 MB
    unsigned*      skey = (unsigned*)p;        p += (size_t)PBM * PL * 4;       // 2.56 MB
    unsigned char* ucnt = (unsigned char*)p;   // 12800*16 = 0.2 MB

    k_sortconv<<<dim3(NCONV + PBM / 4), dim3(256), 0, stream>>>(
        x_e, W, skey, ucnt, Wt);
    k_gatherp <<<dim3(1024),            dim3(512), 0, stream>>>(
        skey, ucnt, emb, M_ws);
    k_hops    <<<dim3(PB),              dim3(1024), 0, stream>>>(x_q, emb, M_ws, uh);
    k_gemm_exp<<<dim3(NT, 2),           dim3(128),  0, stream>>>(uh, Wt, Eh, part);
    k_scale   <<<dim3(PB),              dim3(512),  0, stream>>>(Eh, part, out);
}

// Round 15
// 224.838 us; speedup vs baseline: 1.0976x; 1.0005x over previous
//
#include <hip/hip_runtime.h>
#include <hip/hip_bf16.h>
#include <hip/hip_fp16.h>
#include <math.h>

// Problem constants (MemN2N): B=256, M=50, L=50, V=50257, D=128, HOPS=3
#define PB   256
#define PM   50
#define PL   50
#define PV   50257
#define PD   128
#define PBM  (PB * PM)              // 12800
#define TS   ((size_t)PV * PD)      // one embedding table, elements
#define PEC  0.000625f              // 4/(D*L) = 4/6400
#define NT   786                    // ceil(PV/64) column tiles
#define PVP  (NT * 64)              // 50304 padded vocab
#define NCONV 786                   // convW blocks at front of sortconv launch
#define NCH  16                     // vocab chunks (~1.6 MB window/table)
#define CHW  3142                   // ceil(PV/NCH)
#define UPB  50                     // bm units per gather block

typedef _Float16 f16x8 __attribute__((ext_vector_type(8)));
typedef float    f32x4 __attribute__((ext_vector_type(4)));

// -------------------------------------------------------------------------
// Kernel 0 (fused): blocks 0..785 transpose W -> Wt fp16; rest: per-bm
// 64-lane bitonic sort of keys idx*64+l, plus per-chunk count histogram.
// (r12 proven)
// -------------------------------------------------------------------------
__global__ __launch_bounds__(256) void k_sortconv(const int* __restrict__ xe,
                                                  const float* __restrict__ W,
                                                  unsigned* __restrict__ skey,
                                                  unsigned char* __restrict__ ucnt,
                                                  _Float16* __restrict__ Wt) {
    const int t = threadIdx.x;

    if (blockIdx.x < NCONV) {
        __shared__ float ls[PD][20];
        const bool edge = (blockIdx.x == NCONV - 1);
        #pragma unroll 1
        for (int p = 0; p < 4; ++p) {
            const int c0 = blockIdx.x * 64 + p * 16;
            #pragma unroll
            for (int i = 0; i < 2; ++i) {
                const int e  = t + i * 256;
                const int kk = e >> 2, c4 = (e & 3) * 4;
                const int gc = c0 + c4;
                f32x4 v;
                if (!edge || gc + 3 < PV) {
                    v = *reinterpret_cast<const f32x4*>(W + (size_t)kk * PV + gc);
                } else {
                    v.x = (gc + 0 < PV) ? W[(size_t)kk * PV + gc + 0] : 0.f;
                    v.y = (gc + 1 < PV) ? W[(size_t)kk * PV + gc + 1] : 0.f;
                    v.z = (gc + 2 < PV) ? W[(size_t)kk * PV + gc + 2] : 0.f;
                    v.w = (gc + 3 < PV) ? W[(size_t)kk * PV + gc + 3] : 0.f;
                }
                *reinterpret_cast<f32x4*>(&ls[kk][c4]) = v;
            }
            __syncthreads();
            {
                const int c = t >> 4, k0 = (t & 15) * 8;
                f16x8 v;
                #pragma unroll
                for (int j = 0; j < 8; ++j) v[j] = (_Float16)ls[k0 + j][c];
                *reinterpret_cast<f16x8*>(Wt + (size_t)(c0 + c) * PD + k0) = v;
            }
            __syncthreads();
        }
        return;
    }

    // ---- bitonic sort + chunk histogram: one wave per bm ----
    const int wv   = t >> 6;
    const int lane = t & 63;
    const int bm   = (blockIdx.x - NCONV) * 4 + wv;

    unsigned key = 0xFFFFFFFFu;
    if (lane < PL)
        key = ((unsigned)xe[(size_t)bm * PL + lane] << 6) | (unsigned)lane;

    #pragma unroll
    for (int k = 2; k <= 64; k <<= 1) {
        #pragma unroll
        for (int j = k >> 1; j > 0; j >>= 1) {
            const unsigned other = (unsigned)__shfl_xor((int)key, j);
            const bool up      = ((lane & k) == 0);
            const bool keepMin = (((lane & j) == 0) == up);
            const unsigned mn = key < other ? key : other;
            const unsigned mx = key < other ? other : key;
            key = keepMin ? mn : mx;
        }
    }
    if (lane < PL) skey[(size_t)bm * PL + lane] = key;

    const int ci = (int)((key >> 6) / (unsigned)CHW);
    #pragma unroll
    for (int c = 0; c < NCH; ++c) {
        const unsigned long long m = __ballot(lane < PL && ci == c);
        if (lane == c) ucnt[bm * NCH + c] = (unsigned char)__popcll(m);
    }
}

// -------------------------------------------------------------------------
// Kernel 1: phase-locked persistent gather v4 (r12 + paired units, FIXED
// dummy index). 1024 blocks x 512 thr (4/CU, all co-resident). XCD x=b&7
// owns table x>>1, bm-half x&1. 16-chunk vocab sweep (1.6 MB window, 88%
// L2-absorb measured r12). Units in compile-time pairs (0,1),(2,3),(4,5):
// both units' loads issued before either's FMAs -> 4 rows in flight/wave.
// Exhausted-unit dummy loads now CLAMP to the unit's most recent key
// (bA-1: row touched within the last window -> L2-hit), not key 0 (r14's
// bug: far-behind row, evicted -> FETCH 157->390 MB regression).
// -------------------------------------------------------------------------
__global__ __launch_bounds__(512, 8) void k_gatherp(
        const unsigned* __restrict__ skey,
        const unsigned char* __restrict__ ucnt,
        const float* __restrict__ emb,
        float* __restrict__ Mw) {
    const int b    = blockIdx.x;         // 0..1023
    const int x    = b & 7;              // XCD
    const int k    = x >> 1;             // table 0..3
    const int half = x & 1;
    const int slot = b >> 3;             // 0..127
    const int bm0  = half * 6400 + slot * UPB;

    const int t    = threadIdx.x;
    const int wv   = t >> 6;             // wave 0..7
    const int lane = t & 63;
    const int sub  = lane >> 5;          // subgroup 0/1
    const int d4   = (lane & 31) * 4;

    __shared__ unsigned      skeys[UPB][PL];    // 10 KB
    __shared__ unsigned char scnt[UPB][NCH];    // 0.8 KB

    for (int i = t; i < UPB * PL; i += 512)
        ((unsigned*)skeys)[i] = skey[(size_t)bm0 * PL + i];
    if (t < UPB * NCH / 4)
        ((unsigned*)scnt)[t] = ((const unsigned*)(ucnt + bm0 * NCH))[t];
    __syncthreads();

    const float* tab = emb + (size_t)k * TS;
    const float dd0 = (float)(d4 + 0) - 63.0f;
    const float dd1 = (float)(d4 + 1) - 63.0f;
    const float dd2 = (float)(d4 + 2) - 63.0f;
    const float dd3 = (float)(d4 + 3) - 63.0f;

    // wave wv owns units u = wv + 8*i (i<6 paired; unit 6 only waves 0,1)
    f32x4 acc[7];
    int   cur[7];
    #pragma unroll
    for (int i = 0; i < 7; ++i) {
        acc[i] = (f32x4){0.f, 0.f, 0.f, 0.f};
        cur[i] = 0;
    }

    #pragma unroll 1
    for (int c = 0; c < NCH; ++c) {
        // paired units: 4 rows in flight per wave
        #pragma unroll
        for (int pi = 0; pi < 3; ++pi) {
            const int iA = 2 * pi, iB = iA + 1;
            const int uA = wv + 8 * iA;          // <= 39 < UPB
            const int uB = wv + 8 * iB;          // <= 47 < UPB
            const int nA = (int)scnt[uA][c];
            const int nB = (int)scnt[uB][c];
            const int bA = cur[iA], bB = cur[iB];
            f32x4 aA = acc[iA], aB = acc[iB];
            const int nmax = nA > nB ? nA : nB;
            for (int j = sub; j < nmax; j += 2) {
                const bool dA = (j < nA), dB = (j < nB);
                // dummy -> most recent key (in-window, L2-hot)
                const int idxA = dA ? bA + j : (bA ? bA - 1 : 0);
                const int idxB = dB ? bB + j : (bB ? bB - 1 : 0);
                const unsigned kA = skeys[uA][idxA];
                const unsigned kB = skeys[uB][idxB];
                const f32x4 vA = *reinterpret_cast<const f32x4*>(
                    tab + (size_t)(kA >> 6) * PD + d4);
                const f32x4 vB = *reinterpret_cast<const f32x4*>(
                    tab + (size_t)(kB >> 6) * PD + d4);
                const float pA = dA ? 1.0f : 0.0f;
                const float pB = dB ? 1.0f : 0.0f;
                const float fA = pA * (PEC * ((float)(int)(kA & 63u) - 24.0f));
                const float fB = pB * (PEC * ((float)(int)(kB & 63u) - 24.0f));
                aA.x += (pA + fA * dd0) * vA.x;
                aA.y += (pA + fA * dd1) * vA.y;
                aA.z += (pA + fA * dd2) * vA.z;
                aA.w += (pA + fA * dd3) * vA.w;
                aB.x += (pB + fB * dd0) * vB.x;
                aB.y += (pB + fB * dd1) * vB.y;
                aB.z += (pB + fB * dd2) * vB.z;
                aB.w += (pB + fB * dd3) * vB.w;
            }
            acc[iA] = aA; acc[iB] = aB;
            cur[iA] = bA + nA; cur[iB] = bB + nB;
        }
        // single unit 6 (only waves 0,1): r12's parity loop
        {
            const int u = wv + 48;
            if (u < UPB) {
                const int n    = (int)scnt[u][c];
                const int base = cur[6];
                f32x4 a = acc[6];
                for (int j = sub; j < n; j += 2) {
                    const unsigned k1 = skeys[u][base + j];
                    const f32x4 v1 = *reinterpret_cast<const f32x4*>(
                        tab + (size_t)(k1 >> 6) * PD + d4);
                    const float fl = PEC * ((float)(int)(k1 & 63u) - 24.0f);
                    a.x += (1.0f + fl * dd0) * v1.x;
                    a.y += (1.0f + fl * dd1) * v1.y;
                    a.z += (1.0f + fl * dd2) * v1.z;
                    a.w += (1.0f + fl * dd3) * v1.w;
                }
                acc[6] = a;
                cur[6] = base + n;
            }
        }
    }

    // merge subgroup 1 into subgroup 0, store 512B rows
    #pragma unroll
    for (int i = 0; i < 7; ++i) {
        const int u = wv + 8 * i;
        f32x4 o;
        o.x = __shfl_down(acc[i].x, 32);
        o.y = __shfl_down(acc[i].y, 32);
        o.z = __shfl_down(acc[i].z, 32);
        o.w = __shfl_down(acc[i].w, 32);
        if (u < UPB && sub == 0) {
            const f32x4 s = acc[i] + o;
            *reinterpret_cast<f32x4*>(
                Mw + ((size_t)k * PBM + bm0 + u) * PD + d4) = s;
        }
    }
}

// -------------------------------------------------------------------------
// Kernel 2: per-b u + 3 hops. 256 blocks x 1024 threads (proven r10).
// -------------------------------------------------------------------------
__global__ __launch_bounds__(1024) void k_hops(const int* __restrict__ xq,
                                               const float* __restrict__ emb,
                                               const float* __restrict__ Mw,
                                               _Float16* __restrict__ uh) {
    const int b = blockIdx.x;
    const int t = threadIdx.x;
    const int g = t >> 7;
    const int d = t & 127;

    __shared__ float us[PD];
    __shared__ float ps[64];
    __shared__ float red[8][PD];
    __shared__ int   sidx[PL];

    if (t < PL) sidx[t] = xq[(size_t)b * PL + t];
    __syncthreads();

    {
        const float dd = (float)d - 63.0f;
        float acc = 0.f;
        for (int l = g; l < PL; l += 8)
            acc += (1.0f + PEC * dd * ((float)l - 24.0f)) *
                   emb[(size_t)sidx[l] * PD + d];
        red[g][d] = acc;
    }
    __syncthreads();
    if (t < PD) {
        float s = red[0][t];
        #pragma unroll
        for (int i = 1; i < 8; ++i) s += red[i][t];
        us[t] = s;
    }
    __syncthreads();

    const int lane = t & 63;
    const int wave = t >> 6;

    for (int hop = 0; hop < 3; ++hop) {
        const float* Ma = Mw + ((size_t)hop * PBM + (size_t)b * PM) * PD;
        const float* Mc = Ma + (size_t)PBM * PD;

        for (int m = wave; m < PM; m += 16) {
            const float* row = Ma + (size_t)m * PD;
            float part = row[lane] * us[lane] + row[lane + 64] * us[lane + 64];
            #pragma unroll
            for (int off = 32; off > 0; off >>= 1)
                part += __shfl_down(part, off);
            if (lane == 0) ps[m] = part;
        }
        __syncthreads();

        if (wave == 0) {
            float s = (lane < PM) ? ps[lane] : -INFINITY;
            float mx = s;
            #pragma unroll
            for (int off = 32; off > 0; off >>= 1)
                mx = fmaxf(mx, __shfl_xor(mx, off));
            float e = (lane < PM) ? __expf(s - mx) : 0.f;
            float sm = e;
            #pragma unroll
            for (int off = 32; off > 0; off >>= 1)
                sm += __shfl_xor(sm, off);
            if (lane < PM) ps[lane] = e / sm;
        }
        __syncthreads();

        {
            float o = 0.f;
            for (int m = g; m < PM; m += 8)
                o += ps[m] * Mc[(size_t)m * PD + d];
            red[g][d] = o;
        }
        __syncthreads();
        if (t < PD) {
            float s = red[0][t];
            #pragma unroll
            for (int i = 1; i < 8; ++i) s += red[i][t];
            us[t] += s;
        }
        __syncthreads();
    }

    if (t < PD) uh[(size_t)b * PD + t] = (_Float16)us[t];
}

// -------------------------------------------------------------------------
// Kernel 3: GEMM pass — E = exp(v - tile_max) fp16 (LDS-staged, coalesced
// f16x8 stores), (mx,se) to part. grid (786,2), 128 thr. (proven r10)
// -------------------------------------------------------------------------
__global__ __launch_bounds__(128) void k_gemm_exp(const _Float16* __restrict__ uh,
                                                  const _Float16* __restrict__ Wt,
                                                  _Float16* __restrict__ Eh,
                                                  float* __restrict__ part) {
    const int tile    = blockIdx.x;
    const int colBase = tile * 64;
    const int w       = threadIdx.x >> 6;
    const int l       = threadIdx.x & 63;
    const int lrow    = l & 15;
    const int lk      = (l >> 4) * 8;
    const int rb0     = blockIdx.y * 128;
    const int rowBase = rb0 + w * 64;

    __shared__ _Float16 es[128][72];

    f32x4 acc[4][4];
    #pragma unroll
    for (int i = 0; i < 4; ++i)
        #pragma unroll
        for (int j = 0; j < 4; ++j)
            acc[i][j] = (f32x4){0.f, 0.f, 0.f, 0.f};

    #pragma unroll
    for (int ks = 0; ks < 4; ++ks) {
        const int k0 = ks * 32 + lk;
        f16x8 a[4], bfr[4];
        #pragma unroll
        for (int mi = 0; mi < 4; ++mi)
            a[mi] = *reinterpret_cast<const f16x8*>(
                uh + (size_t)(rowBase + mi * 16 + lrow) * PD + k0);
        #pragma unroll
        for (int ni = 0; ni < 4; ++ni)
            bfr[ni] = *reinterpret_cast<const f16x8*>(
                Wt + (size_t)(colBase + ni * 16 + lrow) * PD + k0);
        #pragma unroll
        for (int mi = 0; mi < 4; ++mi)
            #pragma unroll
            for (int ni = 0; ni < 4; ++ni)
                acc[mi][ni] = __builtin_amdgcn_mfma_f32_16x16x32_f16(
                    a[mi], bfr[ni], acc[mi][ni], 0, 0, 0);
    }

    const int rquad = (l >> 4) * 4;
    #pragma unroll
    for (int mi = 0; mi < 4; ++mi) {
        #pragma unroll
        for (int q = 0; q < 4; ++q) {
            const int row   = rowBase + mi * 16 + rquad + q;
            const int row_l = row - rb0;
            float v[4];
            float mx = -INFINITY;
            #pragma unroll
            for (int j = 0; j < 4; ++j) {
                const int col = colBase + j * 16 + lrow;
                v[j] = (col < PV) ? acc[mi][j][q] : -INFINITY;
                mx = fmaxf(mx, v[j]);
            }
            #pragma unroll
            for (int msk = 1; msk < 16; msk <<= 1)
                mx = fmaxf(mx, __shfl_xor(mx, msk));
            float se = 0.f;
            #pragma unroll
            for (int j = 0; j < 4; ++j) {
                const float e = __expf(v[j] - mx);
                se += e;
                es[row_l][j * 16 + lrow] = (_Float16)e;
            }
            #pragma unroll
            for (int msk = 1; msk < 16; msk <<= 1)
                se += __shfl_xor(se, msk);
            if (lrow == 0) {
                part[((size_t)tile * PB + row) * 2 + 0] = mx;
                part[((size_t)tile * PB + row) * 2 + 1] = se;
            }
        }
    }
    __syncthreads();

    #pragma unroll
    for (int i = 0; i < 8; ++i) {
        const int ch    = threadIdx.x + i * 128;
        const int row_l = ch >> 3, cq = ch & 7;
        const f16x8 v = *reinterpret_cast<const f16x8*>(&es[row_l][cq * 8]);
        *reinterpret_cast<f16x8*>(
            Eh + (size_t)(rb0 + row_l) * PVP + colBase + cq * 8) = v;
    }
}

// -------------------------------------------------------------------------
// Kernel 4: fused merge + scale (proven r10).
// -------------------------------------------------------------------------
__global__ __launch_bounds__(512) void k_scale(const _Float16* __restrict__ Eh,
                                               const float* __restrict__ part,
                                               float* __restrict__ out) {
    const int b = blockIdx.x;
    const int t = threadIdx.x;
    __shared__ float sc[NT];
    __shared__ float wm[8], ws[8];

    float M = -INFINITY, S = 0.f;
    for (int tile = t; tile < NT; tile += 512) {
        const float m = part[((size_t)tile * PB + b) * 2 + 0];
        const float s = part[((size_t)tile * PB + b) * 2 + 1];
        const float nM = fmaxf(M, m);
        S = S * __expf(M - nM) + s * __expf(m - nM);
        M = nM;
    }
    #pragma unroll
    for (int off = 32; off > 0; off >>= 1) {
        const float m2 = __shfl_xor(M, off);
        const float s2 = __shfl_xor(S, off);
        const float nM = fmaxf(M, m2);
        S = S * __expf(M - nM) + s2 * __expf(m2 - nM);
        M = nM;
    }
    if ((t & 63) == 0) { wm[t >> 6] = M; ws[t >> 6] = S; }
    __syncthreads();
    M = -INFINITY; S = 0.f;
    #pragma unroll
    for (int i = 0; i < 8; ++i) {
        const float m = wm[i], s = ws[i];
        const float nM = fmaxf(M, m);
        S = S * __expf(M - nM) + s * __expf(m - nM);
        M = nM;
    }
    const float rinv = 1.0f / S;

    for (int tile = t; tile < NT; tile += 512)
        sc[tile] = __expf(part[((size_t)tile * PB + b) * 2 + 0] - M) * rinv;
    __syncthreads();

    const _Float16* erow = Eh + (size_t)b * PVP;
    float*          orow = out + (size_t)b * PV;

    const int NP = PV >> 1;
    for (int i = t; i < NP; i += 512) {
        const int c = 2 * i;
        const unsigned u = *reinterpret_cast<const unsigned*>(erow + c);
        const _Float16 e0 = ((const _Float16*)&u)[0];
        const _Float16 e1 = ((const _Float16*)&u)[1];
        const float s0 = sc[c >> 6];
        orow[c]     = (float)e0 * s0;
        orow[c + 1] = (float)e1 * s0;
    }
    if (t == 0)
        orow[PV - 1] = (float)erow[PV - 1] * sc[(PV - 1) >> 6];
}

// -------------------------------------------------------------------------
extern "C" void kernel_launch(void* const* d_in, const int* in_sizes, int n_in,
                              void* d_out, int out_size, void* d_ws, size_t ws_size,
                              hipStream_t stream) {
    const int*   x_e = (const int*)d_in[0];    // [B, M, L]
    const int*   x_q = (const int*)d_in[1];    // [B, L]
    const float* emb = (const float*)d_in[2];  // [4, V, D]
    const float* W   = (const float*)d_in[3];  // [D, V]
    float*       out = (float*)d_out;          // [B, V]
    (void)n_in; (void)in_sizes; (void)out_size; (void)ws_size;

    char* p = (char*)d_ws;
    float*         M_ws = (float*)p;           p += (size_t)4 * PBM * PD * 4;   // 26.2 MB
    _Float16*      uh   = (_Float16*)p;        p += (size_t)PB * PD * 2;        // 64 KB
    _Float16*      Wt   = (_Float16*)p;        p += (size_t)PVP * PD * 2;       // 12.9 MB
    float*         part = (float*)p;           p += (size_t)NT * PB * 2 * 4;    // 1.6 MB
    _Float16*      Eh   = (_Float16*)p;        p += (size_t)PB * PVP * 2;       // 25.8 MB
    unsigned*      skey = (unsigned*)p;        p += (size_t)PBM * PL * 4;       // 2.56 MB
    unsigned char* ucnt = (unsigned char*)p;   // 12800*16 = 0.2 MB

    k_sortconv<<<dim3(NCONV + PBM / 4), dim3(256), 0, stream>>>(
        x_e, W, skey, ucnt, Wt);
    k_gatherp <<<dim3(1024),            dim3(512), 0, stream>>>(
        skey, ucnt, emb, M_ws);
    k_hops    <<<dim3(PB),              dim3(1024), 0, stream>>>(x_q, emb, M_ws, uh);
    k_gemm_exp<<<dim3(NT, 2),           dim3(128),  0, stream>>>(uh, Wt, Eh, part);
    k_scale   <<<dim3(PB),              dim3(512),  0, stream>>>(Eh, part, out);
}

// Round 16
// 162.669 us; speedup vs baseline: 1.5171x; 1.3822x over previous
//
#include <hip/hip_runtime.h>
#include <hip/hip_bf16.h>
#include <hip/hip_fp16.h>
#include <math.h>

// Problem constants (MemN2N): B=256, M=50, L=50, V=50257, D=128, HOPS=3
#define PB   256
#define PM   50
#define PL   50
#define PV   50257
#define PD   128
#define PBM  (PB * PM)              // 12800
#define TS   ((size_t)PV * PD)      // one embedding table, elements
#define PEC  0.000625f              // 4/(D*L) = 4/6400
#define NT   786                    // ceil(PV/64) column tiles
#define PVP  (NT * 64)              // 50304 padded vocab
#define NCONV 786                   // convW blocks at front of sortconv launch
#define NCH  16                     // vocab chunks (~1.6 MB window/table)
#define CHW  3142                   // ceil(PV/NCH)
#define UPB  50                     // bm units per gather block

typedef _Float16 f16x8 __attribute__((ext_vector_type(8)));
typedef float    f32x4 __attribute__((ext_vector_type(4)));

// -------------------------------------------------------------------------
// Kernel 0 (fused): blocks 0..785 transpose W -> Wt fp16; rest: per-bm
// 64-lane bitonic sort of keys idx*64+l, plus per-chunk count histogram.
// (r12 proven)
// -------------------------------------------------------------------------
__global__ __launch_bounds__(256) void k_sortconv(const int* __restrict__ xe,
                                                  const float* __restrict__ W,
                                                  unsigned* __restrict__ skey,
                                                  unsigned char* __restrict__ ucnt,
                                                  _Float16* __restrict__ Wt) {
    const int t = threadIdx.x;

    if (blockIdx.x < NCONV) {
        __shared__ float ls[PD][20];
        const bool edge = (blockIdx.x == NCONV - 1);
        #pragma unroll 1
        for (int p = 0; p < 4; ++p) {
            const int c0 = blockIdx.x * 64 + p * 16;
            #pragma unroll
            for (int i = 0; i < 2; ++i) {
                const int e  = t + i * 256;
                const int kk = e >> 2, c4 = (e & 3) * 4;
                const int gc = c0 + c4;
                f32x4 v;
                if (!edge || gc + 3 < PV) {
                    v = *reinterpret_cast<const f32x4*>(W + (size_t)kk * PV + gc);
                } else {
                    v.x = (gc + 0 < PV) ? W[(size_t)kk * PV + gc + 0] : 0.f;
                    v.y = (gc + 1 < PV) ? W[(size_t)kk * PV + gc + 1] : 0.f;
                    v.z = (gc + 2 < PV) ? W[(size_t)kk * PV + gc + 2] : 0.f;
                    v.w = (gc + 3 < PV) ? W[(size_t)kk * PV + gc + 3] : 0.f;
                }
                *reinterpret_cast<f32x4*>(&ls[kk][c4]) = v;
            }
            __syncthreads();
            {
                const int c = t >> 4, k0 = (t & 15) * 8;
                f16x8 v;
                #pragma unroll
                for (int j = 0; j < 8; ++j) v[j] = (_Float16)ls[k0 + j][c];
                *reinterpret_cast<f16x8*>(Wt + (size_t)(c0 + c) * PD + k0) = v;
            }
            __syncthreads();
        }
        return;
    }

    // ---- bitonic sort + chunk histogram: one wave per bm ----
    const int wv   = t >> 6;
    const int lane = t & 63;
    const int bm   = (blockIdx.x - NCONV) * 4 + wv;

    unsigned key = 0xFFFFFFFFu;
    if (lane < PL)
        key = ((unsigned)xe[(size_t)bm * PL + lane] << 6) | (unsigned)lane;

    #pragma unroll
    for (int k = 2; k <= 64; k <<= 1) {
        #pragma unroll
        for (int j = k >> 1; j > 0; j >>= 1) {
            const unsigned other = (unsigned)__shfl_xor((int)key, j);
            const bool up      = ((lane & k) == 0);
            const bool keepMin = (((lane & j) == 0) == up);
            const unsigned mn = key < other ? key : other;
            const unsigned mx = key < other ? other : key;
            key = keepMin ? mn : mx;
        }
    }
    if (lane < PL) skey[(size_t)bm * PL + lane] = key;

    const int ci = (int)((key >> 6) / (unsigned)CHW);
    #pragma unroll
    for (int c = 0; c < NCH; ++c) {
        const unsigned long long m = __ballot(lane < PL && ci == c);
        if (lane == c) ucnt[bm * NCH + c] = (unsigned char)__popcll(m);
    }
}

// -------------------------------------------------------------------------
// Kernel 1: phase-locked persistent gather (r12 proven, byte-identical).
// 1024 blocks x 512 thr (4/CU, all co-resident). XCD x=b&7 owns table
// x>>1, bm-half x&1; slot=b>>3 -> 50 bm. 16-chunk vocab sweep (1.6 MB
// window, 88% L2-absorb measured). Keys+counts in LDS, acc/cursors in
// registers (static unroll), 2 subgroups/wave on alternate keys ->
// 2 rows in flight/wave, 8 waves/SIMD.
// -------------------------------------------------------------------------
__global__ __launch_bounds__(512, 8) void k_gatherp(
        const unsigned* __restrict__ skey,
        const unsigned char* __restrict__ ucnt,
        const float* __restrict__ emb,
        float* __restrict__ Mw) {
    const int b    = blockIdx.x;         // 0..1023
    const int x    = b & 7;              // XCD
    const int k    = x >> 1;             // table 0..3
    const int half = x & 1;
    const int slot = b >> 3;             // 0..127
    const int bm0  = half * 6400 + slot * UPB;

    const int t    = threadIdx.x;
    const int wv   = t >> 6;             // wave 0..7
    const int lane = t & 63;
    const int sub  = lane >> 5;          // subgroup 0/1
    const int d4   = (lane & 31) * 4;

    __shared__ unsigned      skeys[UPB][PL];    // 10 KB
    __shared__ unsigned char scnt[UPB][NCH];    // 0.8 KB

    for (int i = t; i < UPB * PL; i += 512)
        ((unsigned*)skeys)[i] = skey[(size_t)bm0 * PL + i];
    if (t < UPB * NCH / 4)
        ((unsigned*)scnt)[t] = ((const unsigned*)(ucnt + bm0 * NCH))[t];
    __syncthreads();

    const float* tab = emb + (size_t)k * TS;
    const float dd0 = (float)(d4 + 0) - 63.0f;
    const float dd1 = (float)(d4 + 1) - 63.0f;
    const float dd2 = (float)(d4 + 2) - 63.0f;
    const float dd3 = (float)(d4 + 3) - 63.0f;

    // wave wv owns units u = wv + 8*i (i < 7, u < 50)
    f32x4 acc[7];
    int   cur[7];
    #pragma unroll
    for (int i = 0; i < 7; ++i) {
        acc[i] = (f32x4){0.f, 0.f, 0.f, 0.f};
        cur[i] = 0;
    }

    #pragma unroll 1
    for (int c = 0; c < NCH; ++c) {
        #pragma unroll
        for (int i = 0; i < 7; ++i) {
            const int u = wv + 8 * i;
            if (u < UPB) {
                const int n    = (int)scnt[u][c];
                const int base = cur[i];
                f32x4 a = acc[i];
                // subgroups walk alternate keys -> 2 rows in flight
                for (int j = sub; j < n; j += 2) {
                    const unsigned key = skeys[u][base + j];
                    const int   l  = (int)(key & 63u);
                    const f32x4 v  = *reinterpret_cast<const f32x4*>(
                        tab + (size_t)(key >> 6) * PD + d4);
                    const float fl = PEC * ((float)l - 24.0f);
                    a.x += (1.0f + fl * dd0) * v.x;
                    a.y += (1.0f + fl * dd1) * v.y;
                    a.z += (1.0f + fl * dd2) * v.z;
                    a.w += (1.0f + fl * dd3) * v.w;
                }
                acc[i] = a;
                cur[i] = base + n;
            }
        }
    }

    // merge subgroup 1 (lanes 32-63) into subgroup 0, store 512B rows
    #pragma unroll
    for (int i = 0; i < 7; ++i) {
        const int u = wv + 8 * i;
        f32x4 o;
        o.x = __shfl_down(acc[i].x, 32);
        o.y = __shfl_down(acc[i].y, 32);
        o.z = __shfl_down(acc[i].z, 32);
        o.w = __shfl_down(acc[i].w, 32);
        if (u < UPB && sub == 0) {
            const f32x4 s = acc[i] + o;
            *reinterpret_cast<f32x4*>(
                Mw + ((size_t)k * PBM + bm0 + u) * PD + d4) = s;
        }
    }
}

// -------------------------------------------------------------------------
// Kernel 2: per-b u + 3 hops. 256 blocks x 1024 threads (proven r10).
// -------------------------------------------------------------------------
__global__ __launch_bounds__(1024) void k_hops(const int* __restrict__ xq,
                                               const float* __restrict__ emb,
                                               const float* __restrict__ Mw,
                                               _Float16* __restrict__ uh) {
    const int b = blockIdx.x;
    const int t = threadIdx.x;
    const int g = t >> 7;
    const int d = t & 127;

    __shared__ float us[PD];
    __shared__ float ps[64];
    __shared__ float red[8][PD];
    __shared__ int   sidx[PL];

    if (t < PL) sidx[t] = xq[(size_t)b * PL + t];
    __syncthreads();

    {
        const float dd = (float)d - 63.0f;
        float acc = 0.f;
        for (int l = g; l < PL; l += 8)
            acc += (1.0f + PEC * dd * ((float)l - 24.0f)) *
                   emb[(size_t)sidx[l] * PD + d];
        red[g][d] = acc;
    }
    __syncthreads();
    if (t < PD) {
        float s = red[0][t];
        #pragma unroll
        for (int i = 1; i < 8; ++i) s += red[i][t];
        us[t] = s;
    }
    __syncthreads();

    const int lane = t & 63;
    const int wave = t >> 6;

    for (int hop = 0; hop < 3; ++hop) {
        const float* Ma = Mw + ((size_t)hop * PBM + (size_t)b * PM) * PD;
        const float* Mc = Ma + (size_t)PBM * PD;

        for (int m = wave; m < PM; m += 16) {
            const float* row = Ma + (size_t)m * PD;
            float part = row[lane] * us[lane] + row[lane + 64] * us[lane + 64];
            #pragma unroll
            for (int off = 32; off > 0; off >>= 1)
                part += __shfl_down(part, off);
            if (lane == 0) ps[m] = part;
        }
        __syncthreads();

        if (wave == 0) {
            float s = (lane < PM) ? ps[lane] : -INFINITY;
            float mx = s;
            #pragma unroll
            for (int off = 32; off > 0; off >>= 1)
                mx = fmaxf(mx, __shfl_xor(mx, off));
            float e = (lane < PM) ? __expf(s - mx) : 0.f;
            float sm = e;
            #pragma unroll
            for (int off = 32; off > 0; off >>= 1)
                sm += __shfl_xor(sm, off);
            if (lane < PM) ps[lane] = e / sm;
        }
        __syncthreads();

        {
            float o = 0.f;
            for (int m = g; m < PM; m += 8)
                o += ps[m] * Mc[(size_t)m * PD + d];
            red[g][d] = o;
        }
        __syncthreads();
        if (t < PD) {
            float s = red[0][t];
            #pragma unroll
            for (int i = 1; i < 8; ++i) s += red[i][t];
            us[t] += s;
        }
        __syncthreads();
    }

    if (t < PD) uh[(size_t)b * PD + t] = (_Float16)us[t];
}

// -------------------------------------------------------------------------
// Kernel 3: GEMM pass — E = exp(v - tile_max) fp16 (LDS-staged, coalesced
// f16x8 stores), (mx,se) to part. grid (786,2), 128 thr. (proven r10)
// -------------------------------------------------------------------------
__global__ __launch_bounds__(128) void k_gemm_exp(const _Float16* __restrict__ uh,
                                                  const _Float16* __restrict__ Wt,
                                                  _Float16* __restrict__ Eh,
                                                  float* __restrict__ part) {
    const int tile    = blockIdx.x;
    const int colBase = tile * 64;
    const int w       = threadIdx.x >> 6;
    const int l       = threadIdx.x & 63;
    const int lrow    = l & 15;
    const int lk      = (l >> 4) * 8;
    const int rb0     = blockIdx.y * 128;
    const int rowBase = rb0 + w * 64;

    __shared__ _Float16 es[128][72];

    f32x4 acc[4][4];
    #pragma unroll
    for (int i = 0; i < 4; ++i)
        #pragma unroll
        for (int j = 0; j < 4; ++j)
            acc[i][j] = (f32x4){0.f, 0.f, 0.f, 0.f};

    #pragma unroll
    for (int ks = 0; ks < 4; ++ks) {
        const int k0 = ks * 32 + lk;
        f16x8 a[4], bfr[4];
        #pragma unroll
        for (int mi = 0; mi < 4; ++mi)
            a[mi] = *reinterpret_cast<const f16x8*>(
                uh + (size_t)(rowBase + mi * 16 + lrow) * PD + k0);
        #pragma unroll
        for (int ni = 0; ni < 4; ++ni)
            bfr[ni] = *reinterpret_cast<const f16x8*>(
                Wt + (size_t)(colBase + ni * 16 + lrow) * PD + k0);
        #pragma unroll
        for (int mi = 0; mi < 4; ++mi)
            #pragma unroll
            for (int ni = 0; ni < 4; ++ni)
                acc[mi][ni] = __builtin_amdgcn_mfma_f32_16x16x32_f16(
                    a[mi], bfr[ni], acc[mi][ni], 0, 0, 0);
    }

    const int rquad = (l >> 4) * 4;
    #pragma unroll
    for (int mi = 0; mi < 4; ++mi) {
        #pragma unroll
        for (int q = 0; q < 4; ++q) {
            const int row   = rowBase + mi * 16 + rquad + q;
            const int row_l = row - rb0;
            float v[4];
            float mx = -INFINITY;
            #pragma unroll
            for (int j = 0; j < 4; ++j) {
                const int col = colBase + j * 16 + lrow;
                v[j] = (col < PV) ? acc[mi][j][q] : -INFINITY;
                mx = fmaxf(mx, v[j]);
            }
            #pragma unroll
            for (int msk = 1; msk < 16; msk <<= 1)
                mx = fmaxf(mx, __shfl_xor(mx, msk));
            float se = 0.f;
            #pragma unroll
            for (int j = 0; j < 4; ++j) {
                const float e = __expf(v[j] - mx);
                se += e;
                es[row_l][j * 16 + lrow] = (_Float16)e;
            }
            #pragma unroll
            for (int msk = 1; msk < 16; msk <<= 1)
                se += __shfl_xor(se, msk);
            if (lrow == 0) {
                part[((size_t)tile * PB + row) * 2 + 0] = mx;
                part[((size_t)tile * PB + row) * 2 + 1] = se;
            }
        }
    }
    __syncthreads();

    #pragma unroll
    for (int i = 0; i < 8; ++i) {
        const int ch    = threadIdx.x + i * 128;
        const int row_l = ch >> 3, cq = ch & 7;
        const f16x8 v = *reinterpret_cast<const f16x8*>(&es[row_l][cq * 8]);
        *reinterpret_cast<f16x8*>(
            Eh + (size_t)(rb0 + row_l) * PVP + colBase + cq * 8) = v;
    }
}

// -------------------------------------------------------------------------
// Kernel 4: fused merge + scale (proven r10).
// -------------------------------------------------------------------------
__global__ __launch_bounds__(512) void k_scale(const _Float16* __restrict__ Eh,
                                               const float* __restrict__ part,
                                               float* __restrict__ out) {
    const int b = blockIdx.x;
    const int t = threadIdx.x;
    __shared__ float sc[NT];
    __shared__ float wm[8], ws[8];

    float M = -INFINITY, S = 0.f;
    for (int tile = t; tile < NT; tile += 512) {
        const float m = part[((size_t)tile * PB + b) * 2 + 0];
        const float s = part[((size_t)tile * PB + b) * 2 + 1];
        const float nM = fmaxf(M, m);
        S = S * __expf(M - nM) + s * __expf(m - nM);
        M = nM;
    }
    #pragma unroll
    for (int off = 32; off > 0; off >>= 1) {
        const float m2 = __shfl_xor(M, off);
        const float s2 = __shfl_xor(S, off);
        const float nM = fmaxf(M, m2);
        S = S * __expf(M - nM) + s2 * __expf(m2 - nM);
        M = nM;
    }
    if ((t & 63) == 0) { wm[t >> 6] = M; ws[t >> 6] = S; }
    __syncthreads();
    M = -INFINITY; S = 0.f;
    #pragma unroll
    for (int i = 0; i < 8; ++i) {
        const float m = wm[i], s = ws[i];
        const float nM = fmaxf(M, m);
        S = S * __expf(M - nM) + s * __expf(m - nM);
        M = nM;
    }
    const float rinv = 1.0f / S;

    for (int tile = t; tile < NT; tile += 512)
        sc[tile] = __expf(part[((size_t)tile * PB + b) * 2 + 0] - M) * rinv;
    __syncthreads();

    const _Float16* erow = Eh + (size_t)b * PVP;
    float*          orow = out + (size_t)b * PV;

    const int NP = PV >> 1;
    for (int i = t; i < NP; i += 512) {
        const int c = 2 * i;
        const unsigned u = *reinterpret_cast<const unsigned*>(erow + c);
        const _Float16 e0 = ((const _Float16*)&u)[0];
        const _Float16 e1 = ((const _Float16*)&u)[1];
        const float s0 = sc[c >> 6];
        orow[c]     = (float)e0 * s0;
        orow[c + 1] = (float)e1 * s0;
    }
    if (t == 0)
        orow[PV - 1] = (float)erow[PV - 1] * sc[(PV - 1) >> 6];
}

// -------------------------------------------------------------------------
extern "C" void kernel_launch(void* const* d_in, const int* in_sizes, int n_in,
                              void* d_out, int out_size, void* d_ws, size_t ws_size,
                              hipStream_t stream) {
    const int*   x_e = (const int*)d_in[0];    // [B, M, L]
    const int*   x_q = (const int*)d_in[1];    // [B, L]
    const float* emb = (const float*)d_in[2];  // [4, V, D]
    const float* W   = (const float*)d_in[3];  // [D, V]
    float*       out = (float*)d_out;          // [B, V]
    (void)n_in; (void)in_sizes; (void)out_size; (void)ws_size;

    char* p = (char*)d_ws;
    float*         M_ws = (float*)p;           p += (size_t)4 * PBM * PD * 4;   // 26.2 MB
    _Float16*      uh   = (_Float16*)p;        p += (size_t)PB * PD * 2;        // 64 KB
    _Float16*      Wt   = (_Float16*)p;        p += (size_t)PVP * PD * 2;       // 12.9 MB
    float*         part = (float*)p;           p += (size_t)NT * PB * 2 * 4;    // 1.6 MB
    _Float16*      Eh   = (_Float16*)p;        p += (size_t)PB * PVP * 2;       // 25.8 MB
    unsigned*      skey = (unsigned*)p;        p += (size_t)PBM * PL * 4;       // 2.56 MB
    unsigned char* ucnt = (unsigned char*)p;   // 12800*16 = 0.2 MB

    k_sortconv<<<dim3(NCONV + PBM / 4), dim3(256), 0, stream>>>(
        x_e, W, skey, ucnt, Wt);
    k_gatherp <<<dim3(1024),            dim3(512), 0, stream>>>(
        skey, ucnt, emb, M_ws);
    k_hops    <<<dim3(PB),              dim3(1024), 0, stream>>>(x_q, emb, M_ws, uh);
    k_gemm_exp<<<dim3(NT, 2),           dim3(128),  0, stream>>>(uh, Wt, Eh, part);
    k_scale   <<<dim3(PB),              dim3(512),  0, stream>>>(Eh, part, out);
}